// Round 7
// baseline (40.420 us; speedup 1.0000x reference)
//
#include <hip/hip_runtime.h>
#include <math.h>

// Dims fixed by reference setup_inputs():
//   x   : (NS=1024, NN=192) f32 in {-1,+1}
//   W2  : (DD=24)           f32
//   W3  : (DD, DD)          f32
//   phi : (NN, 2)           f32
//   nd  : (NN, NN)          i32 in [0, DD), SYMMETRIC
// out  : (NS,) f32 = J2 + J3 + logmf
//
// c[j,r] = sum_i x_i [nd[j,i]==r] = 2*popc(M[j][r] & P[n]) - popc(M[j][r])
// out[n] = sum_j [ x_j*(0.5*<c_j,W2> + c_j^T W3 c_j) + log(phi[j, x_j>0]) ]
//
// SINGLE kernel node (bench is node-overhead-dominated: 1 node=25.7us,
// 2 nodes=28-32us, memset+1=35us regardless of actual GPU work).
// Cross-block j-reduction via last-arriver handshake on a device-global
// counter (not poisoned by harness; statically 0; reset to 0 by the last
// block each call -> deterministic, replay-safe, no spin, no deadlock).

#define NS 1024
#define NN 192
#define DD 24
#define NBLK (16 * 24)

typedef unsigned long long ull;

__device__ int g_counter = 0;   // module-scope: init 0 at load, kept 0 across calls

__global__ __launch_bounds__(512) void fused_kernel(
    const float* __restrict__ x,
    const float* __restrict__ W2,
    const float* __restrict__ W3,
    const float* __restrict__ phi,
    const int*   __restrict__ nd,
    float* __restrict__ partial,    // ws: [24][NS] f32
    float* __restrict__ out)        // [NS]
{
    const int tid  = threadIdx.x;
    const int lane = tid & 63;
    const int wv   = tid >> 6;          // 0..7
    const int n0   = blockIdx.x * 64;
    const int by   = blockIdx.y;
    const int j    = by * 8 + wv;       // wave-uniform

    __shared__ unsigned Pp[64][6];      // sign bits per sample
    __shared__ unsigned Msk[8][24][8];  // per-j,r: 6 mask words, [6]=-(float)cnt
    __shared__ float    part[8][64];
    __shared__ int      is_last;

    // ---- Phase A: wave wv packs samples wv*8 .. wv*8+7 ----
    #pragma unroll
    for (int q = 0; q < 8; ++q) {
        const int s = wv * 8 + q;
        const float* xr = &x[(size_t)(n0 + s) * NN];
        unsigned keep = 0;
        #pragma unroll
        for (int c = 0; c < 3; ++c) {
            const float v = xr[c * 64 + lane];
            const ull m = __ballot(v > 0.0f);
            const unsigned lo = (unsigned)m, hi = (unsigned)(m >> 32);
            if (lane == 2 * c)     keep = lo;
            if (lane == 2 * c + 1) keep = hi;
        }
        if (lane < 6) Pp[s][lane] = keep;
    }

    // ---- Phase B: masks for this wave's j ----
    {
        const int* ndr = &nd[(size_t)j * NN];
        #pragma unroll
        for (int c = 0; c < 3; ++c) {
            const int ndv = ndr[c * 64 + lane];
            unsigned wlo = 0, whi = 0;
            #pragma unroll
            for (int r = 0; r < DD; ++r) {
                const ull m = __ballot(ndv == r);
                if (lane == r) { wlo = (unsigned)m; whi = (unsigned)(m >> 32); }
            }
            if (lane < DD) {
                Msk[wv][lane][2 * c]     = wlo;
                Msk[wv][lane][2 * c + 1] = whi;
            }
        }
    }
    __syncthreads();

    // ---- Phase B2: negated popcounts (one thread per (j_local, r)) ----
    if (tid < 8 * DD) {
        const int jl = tid / DD, r = tid % DD;
        int cnt = 0;
        #pragma unroll
        for (int w = 0; w < 6; ++w) cnt += __popc(Msk[jl][r][w]);
        Msk[jl][r][6] = __float_as_uint(-(float)cnt);
    }
    __syncthreads();

    // ---- Phase C ----
    const unsigned p0 = Pp[lane][0], p1 = Pp[lane][1], p2 = Pp[lane][2];
    const unsigned p3 = Pp[lane][3], p4 = Pp[lane][4], p5 = Pp[lane][5];

    float c[DD];
    #pragma unroll
    for (int r = 0; r < DD; ++r) {
        const unsigned m0 = Msk[wv][r][0], m1 = Msk[wv][r][1], m2 = Msk[wv][r][2];
        const unsigned m3 = Msk[wv][r][3], m4 = Msk[wv][r][4], m5 = Msk[wv][r][5];
        const float ncnt  = __uint_as_float(Msk[wv][r][6]);
        const int pc = __popc(m0 & p0) + __popc(m1 & p1) + __popc(m2 & p2)
                     + __popc(m3 & p3) + __popc(m4 & p4) + __popc(m5 & p5);
        c[r] = fmaf(2.0f, (float)pc, ncnt);
    }

    // quadratic form + W2 dot; W3/W2 uniform-addressed -> scalar-pipe operands
    float q = 0.0f, l2 = 0.0f;
    #pragma unroll
    for (int r = 0; r < DD; ++r) {
        float t = 0.0f;
        #pragma unroll
        for (int s = 0; s < DD; ++s) t = fmaf(W3[r * DD + s], c[s], t);
        q  = fmaf(c[r], t, q);
        l2 = fmaf(W2[r], c[r], l2);
    }

    // sign of x[n, j] = bit j of P; phi-log folded in per (n, j)
    const int w = j >> 5, bpos = j & 31;
    unsigned pw = (w == 0) ? p0 : (w == 1) ? p1 : (w == 2) ? p2
                : (w == 3) ? p3 : (w == 4) ? p4 : p5;
    const int   pos = (int)((pw >> bpos) & 1u);
    const float xj  = pos ? 1.0f : -1.0f;
    const float lp0 = logf(phi[j * 2 + 0]);
    const float lp1 = logf(phi[j * 2 + 1]);

    const float acc = xj * fmaf(0.5f, l2, q) + (pos ? lp1 : lp0);

    part[wv][lane] = acc;
    __syncthreads();

    // ---- block partial -> plain store; last-arriver handshake ----
    if (wv == 0) {
        float s = part[0][lane] + part[1][lane] + part[2][lane] + part[3][lane]
                + part[4][lane] + part[5][lane] + part[6][lane] + part[7][lane];
        partial[by * NS + n0 + lane] = s;
        __threadfence();                       // release: partials before counter
        if (lane == 0) {
            const int old = atomicAdd(&g_counter, 1);   // device-scope
            is_last = (old == NBLK - 1) ? 1 : 0;
        }
    }
    __syncthreads();

    // ---- the last block reduces all samples and resets the counter ----
    if (is_last) {
        __threadfence();                       // acquire: see all partials
        #pragma unroll
        for (int rep = 0; rep < NS / 512; ++rep) {
            const int n = rep * 512 + tid;
            float s = 0.0f;
            #pragma unroll
            for (int g = 0; g < 24; ++g) s += partial[g * NS + n];  // coalesced
            out[n] = s;
        }
        if (tid == 0) g_counter = 0;           // restore invariant for next call
    }
}

extern "C" void kernel_launch(void* const* d_in, const int* in_sizes, int n_in,
                              void* d_out, int out_size, void* d_ws, size_t ws_size,
                              hipStream_t stream) {
    const float* x   = (const float*)d_in[0];
    const float* W2  = (const float*)d_in[1];
    const float* W3  = (const float*)d_in[2];
    const float* phi = (const float*)d_in[3];
    const int*   nd  = (const int*)d_in[4];
    float* out = (float*)d_out;
    float* partial = (float*)d_ws;   // 24*NS*4 = 96 KB

    const int ns = in_sizes[0] / NN;   // 1024
    fused_kernel<<<dim3(ns / 64, NN / 8), 512, 0, stream>>>(x, W2, W3, phi, nd,
                                                            partial, out);
}